// Round 2
// baseline (770.176 us; speedup 1.0000x reference)
//
#include <hip/hip_runtime.h>

// B=32, IN=16, C=8192, U=32, K=16, 3 routing iterations.
#define CC   8192
#define UU   32
#define BB   32
#define INU  16
#define UK   512
#define CPB  32      // channels per block
#define NBLK 256     // CC/CPB == #CUs
#define XS_STRIDE 528  // floats per staged channel (512 + 16 pad)

// DPP-based partial butterfly add (VALU pipe, not LDS).
template <int CTRL>
__device__ __forceinline__ float dpp_add(float x) {
  int p = __builtin_amdgcn_update_dpp(0, __float_as_int(x), CTRL, 0xF, 0xF, true);
  return x + __int_as_float(p);
}

// Lane map: k = lane&15, bg = lane>>4 (b-group of 8). Wave w owns u = w*4..w*4+3.
// Thread registers: 4 W-rows (u x its k), uh[4][8], Sl[4][8], v[4][8].
// Per channel c: u_hat -> ap (dot with v) -> 64-lane reduce -> e=exp(b+a) -> S += e*u_hat.
// iter0: v=0, b_old=0 (=> e=1, uniform softmax) exactly matching iteration 1.
__global__ __launch_bounds__(512, 2) void fused_pass(
    const float* __restrict__ x, const float* __restrict__ W,
    const float* __restrict__ v_in, float* __restrict__ b_io,
    float* __restrict__ S, float* __restrict__ Z, const int iter0)
{
    __shared__ float xs[16 * XS_STRIDE];

    const int t  = threadIdx.x;
    const int w  = t >> 6;        // wave 0..7
    const int l  = t & 63;
    const int k  = l & 15;
    const int bg = l >> 4;        // 0..3
    const int u0 = w * 4;
    const int c0 = blockIdx.x * CPB;

    float v[4][8], Sl[4][8];
#pragma unroll
    for (int j = 0; j < 4; ++j)
#pragma unroll
      for (int bb = 0; bb < 8; ++bb) Sl[j][bb] = 0.f;

    if (iter0) {
#pragma unroll
      for (int j = 0; j < 4; ++j)
#pragma unroll
        for (int bb = 0; bb < 8; ++bb) v[j][bb] = 0.f;
    } else {
#pragma unroll
      for (int j = 0; j < 4; ++j)
#pragma unroll
        for (int bb = 0; bb < 8; ++bb)
          v[j][bb] = v_in[(bg * 8 + bb) * UK + (u0 + j) * 16 + k];
    }
    float zloc[4] = {0.f, 0.f, 0.f, 0.f};

    for (int cc = 0; cc < CPB; ++cc) {
        if ((cc & 15) == 0) {
            __syncthreads();
            const int cbase = c0 + (cc & ~15);
#pragma unroll
            for (int jj = 0; jj < 16; ++jj) {
                int idx = jj * 512 + t;
                int ccl = idx & 15;
                int bi  = idx >> 4;          // b*16 + i
                int b   = bi >> 4, i = bi & 15;
                // layout [ccl][bb][bg][i]: bg-groups 16 banks apart -> <=2-way conflict
                xs[ccl * XS_STRIDE + (b & 7) * 64 + (b >> 3) * 16 + i] = x[bi * CC + cbase + ccl];
            }
            __syncthreads();
        }

        const int c = c0 + cc;

        // b_old prefetch (broadcast load, hidden under the FMA block)
        float bold[4] = {0.f, 0.f, 0.f, 0.f};
        if (!iter0) {
#pragma unroll
            for (int j = 0; j < 4; ++j) bold[j] = b_io[(size_t)c * UU + u0 + j];
        }

        // W rows for this c: row_j = (u0+j)*16 + k, 16 floats each.
        float4 wq[4][4];
        {
            const float4* wp = (const float4*)(W + ((size_t)c * UK + (size_t)u0 * 16 + k) * INU);
#pragma unroll
            for (int j = 0; j < 4; ++j)
#pragma unroll
                for (int q = 0; q < 4; ++q) wq[j][q] = wp[j * 64 + q];
        }

        float uh[4][8];
        float ap[4] = {0.f, 0.f, 0.f, 0.f};
        const float* xrow = &xs[(cc & 15) * XS_STRIDE + bg * 16];
#pragma unroll
        for (int bb = 0; bb < 8; ++bb) {
            const float4* xr = (const float4*)(xrow + bb * 64);
            float4 x0 = xr[0], x1 = xr[1], x2 = xr[2], x3 = xr[3];
#pragma unroll
            for (int j = 0; j < 4; ++j) {
                float h;
                h = wq[j][0].x * x0.x;
                h = fmaf(wq[j][0].y, x0.y, h); h = fmaf(wq[j][0].z, x0.z, h); h = fmaf(wq[j][0].w, x0.w, h);
                h = fmaf(wq[j][1].x, x1.x, h); h = fmaf(wq[j][1].y, x1.y, h);
                h = fmaf(wq[j][1].z, x1.z, h); h = fmaf(wq[j][1].w, x1.w, h);
                h = fmaf(wq[j][2].x, x2.x, h); h = fmaf(wq[j][2].y, x2.y, h);
                h = fmaf(wq[j][2].z, x2.z, h); h = fmaf(wq[j][2].w, x2.w, h);
                h = fmaf(wq[j][3].x, x3.x, h); h = fmaf(wq[j][3].y, x3.y, h);
                h = fmaf(wq[j][3].z, x3.z, h); h = fmaf(wq[j][3].w, x3.w, h);
                uh[j][bb] = h;
                ap[j] = fmaf(h, v[j][bb], ap[j]);
            }
        }

        // 64-lane sum: 16-lane row via DPP (masks {1,2,7,15} span the row), then xor16/32.
#pragma unroll
        for (int j = 0; j < 4; ++j) {
            float a = ap[j];
            a = dpp_add<0xB1>(a);    // quad_perm [1,0,3,2] : ^1
            a = dpp_add<0x4E>(a);    // quad_perm [2,3,0,1] : ^2
            a = dpp_add<0x141>(a);   // row_half_mirror     : ^7
            a = dpp_add<0x140>(a);   // row_mirror          : ^15
            a += __shfl_xor(a, 16);
            a += __shfl_xor(a, 32);
            ap[j] = a;
        }

#pragma unroll
        for (int j = 0; j < 4; ++j) {
            float bnew = bold[j] + ap[j] * (1.0f / 32.0f);
            float e = __expf(bnew);
            zloc[j] += e;
            if (l == 0) b_io[(size_t)c * UU + u0 + j] = bnew;
#pragma unroll
            for (int bb = 0; bb < 8; ++bb) Sl[j][bb] = fmaf(e, uh[j][bb], Sl[j][bb]);
        }
    }

    // Flush partial S (each (b,uk) owned by exactly one thread per block -> 256-way atomics)
#pragma unroll
    for (int j = 0; j < 4; ++j)
#pragma unroll
        for (int bb = 0; bb < 8; ++bb)
            atomicAdd(S + (bg * 8 + bb) * UK + (u0 + j) * 16 + k, Sl[j][bb]);
    if (l == 0) {
#pragma unroll
        for (int j = 0; j < 4; ++j) atomicAdd(Z + u0 + j, zloc[j]);
    }
}

// s = S/Z ; mag_sq[b,k] = sum_u s^2 (reference sums over num_units axis);
// v = mag_sq/(1+mag_sq) * s/mag.
__global__ void squash_k(const float* __restrict__ S, const float* __restrict__ Z,
                         float* __restrict__ vout)
{
    __shared__ float z_sh[UU];
    __shared__ float s2_sh[UK];
    __shared__ float mag_sh[16];

    const int b = blockIdx.x;   // 32
    const int t = threadIdx.x;  // 512 = uk

    if (t < UU) z_sh[t] = Z[t];
    float ssum = S[b * UK + t];
    __syncthreads();

    float s = ssum / z_sh[t >> 4];
    s2_sh[t] = s * s;
    __syncthreads();

    if (t < 16) {
        float m = 0.f;
        for (int uu = 0; uu < UU; ++uu) m += s2_sh[uu * 16 + t];
        mag_sh[t] = m;
    }
    __syncthreads();

    float msq = mag_sh[t & 15];
    float out = (msq / (1.0f + msq)) * s / sqrtf(msq);
    vout[b * UK + t] = out;
}

extern "C" void kernel_launch(void* const* d_in, const int* in_sizes, int n_in,
                              void* d_out, int out_size, void* d_ws, size_t ws_size,
                              hipStream_t stream)
{
    const float* x = (const float*)d_in[0];   // (B, IN, C)
    const float* W = (const float*)d_in[1];   // (C, U, K, IN)
    float* out = (float*)d_out;               // (B, U, K, 1)

    char* ws = (char*)d_ws;
    const size_t SLOT = 65536 + 256;          // S (64KB) + Z (padded)
    float* vb  = (float*)(ws + 3 * SLOT);
    float* bio = (float*)(ws + 3 * SLOT + 65536);

    // one memset zeroes all three S/Z slots (pass p accumulates into slot p)
    hipMemsetAsync(ws, 0, 3 * SLOT, stream);

    for (int pass = 0; pass < 3; ++pass) {
        float* S = (float*)(ws + pass * SLOT);
        float* Z = (float*)(ws + pass * SLOT + 65536);
        fused_pass<<<NBLK, 512, 0, stream>>>(x, W, vb, bio, S, Z, pass == 0 ? 1 : 0);
        squash_k<<<BB, 512, 0, stream>>>(S, Z, (pass == 2) ? out : vb);
    }
}